// Round 1
// baseline (1261.367 us; speedup 1.0000x reference)
//
#include <hip/hip_runtime.h>

#define EMB_D 64

// ---- kernels ----------------------------------------------------------------

// Per-edge degree accumulation: deg[u] += 1, deg[num_users + i] += 1
__global__ void lgcn_deg(const int* __restrict__ u_idx, const int* __restrict__ i_idx,
                         float* __restrict__ deg, int E, int num_users) {
    int e = blockIdx.x * blockDim.x + threadIdx.x;
    if (e < E) {
        atomicAdd(&deg[u_idx[e]], 1.0f);
        atomicAdd(&deg[num_users + i_idx[e]], 1.0f);
    }
}

// dis[n] = deg>0 ? rsqrt(deg) : 0   (in place)
__global__ void lgcn_dis(float* __restrict__ deg, int N) {
    int n = blockIdx.x * blockDim.x + threadIdx.x;
    if (n < N) {
        float dv = deg[n];
        deg[n] = dv > 0.0f ? rsqrtf(dv) : 0.0f;
    }
}

// One 64-lane wave per edge; lane = embedding dim.
// Reads source rows from (xu, xi) — xu indexed by user id, xi by item id —
// and scatter-adds both message directions into out[N, 64].
// w = dis[u] * dis[ig] * scale
__global__ void lgcn_smooth(const int* __restrict__ u_idx, const int* __restrict__ i_idx,
                            const float* __restrict__ dis,
                            const float* __restrict__ xu, const float* __restrict__ xi,
                            float* __restrict__ out,
                            int E, int num_users, float scale) {
    int e = blockIdx.x * (blockDim.x >> 6) + (threadIdx.x >> 6);
    int lane = threadIdx.x & 63;
    if (e >= E) return;
    int u = u_idx[e];
    int iv = i_idx[e];
    int ig = num_users + iv;
    float w = dis[u] * dis[ig] * scale;
    float a = xu[(size_t)u * EMB_D + lane];   // x[u, lane]
    float b = xi[(size_t)iv * EMB_D + lane];  // x[ig, lane]
    atomicAdd(&out[(size_t)ig * EMB_D + lane], w * a);
    atomicAdd(&out[(size_t)u * EMB_D + lane], w * b);
}

// out = (2*x0 + 2*x1) / 3   elementwise, x0 split across u_emb / i_emb
__global__ void lgcn_combine(const float* __restrict__ u_emb, const float* __restrict__ i_emb,
                             const float* __restrict__ x1, float* __restrict__ out,
                             int nuD, int totD) {
    int i = blockIdx.x * blockDim.x + threadIdx.x;
    if (i < totD) {
        float x0 = (i < nuD) ? u_emb[i] : i_emb[i - nuD];
        out[i] = (2.0f * x0 + 2.0f * x1[i]) * (1.0f / 3.0f);
    }
}

// ---- launch -----------------------------------------------------------------

extern "C" void kernel_launch(void* const* d_in, const int* in_sizes, int n_in,
                              void* d_out, int out_size, void* d_ws, size_t ws_size,
                              hipStream_t stream) {
    const float* u_emb = (const float*)d_in[0];
    const float* i_emb = (const float*)d_in[1];
    const int*   u_idx = (const int*)d_in[2];
    const int*   i_idx = (const int*)d_in[3];
    float* out = (float*)d_out;

    const int num_users = in_sizes[0] / EMB_D;
    const int num_items = in_sizes[1] / EMB_D;
    const int E = in_sizes[2];
    const int N = num_users + num_items;
    const int totD = N * EMB_D;
    const int nuD = num_users * EMB_D;

    // workspace layout: dis[N] | x1[N*64]
    float* dis = (float*)d_ws;
    size_t dis_bytes = ((size_t)N * 4 + 1023) & ~(size_t)1023;
    float* x1 = (float*)((char*)d_ws + dis_bytes);

    // zero accumulators (ws is re-poisoned to 0xAA before every launch)
    hipMemsetAsync(dis, 0, (size_t)N * 4, stream);
    hipMemsetAsync(x1, 0, (size_t)totD * 4, stream);

    // 1) degrees
    {
        int blk = 256, grid = (E + blk - 1) / blk;
        lgcn_deg<<<grid, blk, 0, stream>>>(u_idx, i_idx, dis, E, num_users);
    }
    // 2) dis = rsqrt(deg)
    {
        int blk = 256, grid = (N + blk - 1) / blk;
        lgcn_dis<<<grid, blk, 0, stream>>>(dis, N);
    }
    // 3) x1 = smooth(x0); x0 rows come from u_emb / i_emb directly
    {
        int edges_per_blk = 256 / 64;
        int grid = (E + edges_per_blk - 1) / edges_per_blk;
        lgcn_smooth<<<grid, 256, 0, stream>>>(u_idx, i_idx, dis, u_emb, i_emb, x1,
                                              E, num_users, 1.0f);
    }
    // 4) out = (2*x0 + 2*x1)/3
    {
        int blk = 256, grid = (totD + blk - 1) / blk;
        lgcn_combine<<<grid, blk, 0, stream>>>(u_emb, i_emb, x1, out, nuD, totD);
    }
    // 5) out += (1/3) * smooth(x1)   (x2 contribution, no x2 buffer needed)
    {
        int edges_per_blk = 256 / 64;
        int grid = (E + edges_per_blk - 1) / edges_per_blk;
        lgcn_smooth<<<grid, 256, 0, stream>>>(u_idx, i_idx, dis, x1, x1 + (size_t)nuD, out,
                                              E, num_users, 1.0f / 3.0f);
    }
}

// Round 2
// 767.132 us; speedup vs baseline: 1.6443x; 1.6443x over previous
//
#include <hip/hip_runtime.h>

#define EMB_D 64
#define SCAN_BLOCK 256
#define SCAN_ITEMS 4            // 1024 elements per scan block

// ---- CSR build --------------------------------------------------------------

// degree histogram (int atomics into 800 KB, L2-resident)
__global__ void k_hist(const int* __restrict__ u_idx, const int* __restrict__ i_idx,
                       int* __restrict__ counts, int E, int num_users) {
    int e = blockIdx.x * blockDim.x + threadIdx.x;
    if (e < E) {
        atomicAdd(&counts[u_idx[e]], 1);
        atomicAdd(&counts[num_users + i_idx[e]], 1);
    }
}

// dis[n] = deg>0 ? rsqrt(deg) : 0
__global__ void k_dis(const int* __restrict__ counts, float* __restrict__ dis, int N) {
    int n = blockIdx.x * blockDim.x + threadIdx.x;
    if (n < N) {
        int c = counts[n];
        dis[n] = c > 0 ? rsqrtf((float)c) : 0.0f;
    }
}

// 3-kernel exclusive scan: counts[N] -> B[N]
__global__ void k_scan1(const int* __restrict__ in, int* __restrict__ out,
                        int* __restrict__ partials, int n) {
    __shared__ int sdata[SCAN_BLOCK];
    int idx = blockIdx.x * (SCAN_BLOCK * SCAN_ITEMS) + threadIdx.x * SCAN_ITEMS;
    int v[SCAN_ITEMS];
    int s = 0;
    for (int k = 0; k < SCAN_ITEMS; k++) {
        v[k] = (idx + k < n) ? in[idx + k] : 0;
        s += v[k];
    }
    sdata[threadIdx.x] = s;
    __syncthreads();
    for (int off = 1; off < SCAN_BLOCK; off <<= 1) {
        int t = (threadIdx.x >= off) ? sdata[threadIdx.x - off] : 0;
        __syncthreads();
        sdata[threadIdx.x] += t;
        __syncthreads();
    }
    int incl = sdata[threadIdx.x];
    int excl = incl - s;
    if (threadIdx.x == SCAN_BLOCK - 1) partials[blockIdx.x] = incl;
    int run = excl;
    for (int k = 0; k < SCAN_ITEMS; k++) {
        if (idx + k < n) out[idx + k] = run;
        run += v[k];
    }
}

__global__ void k_scan2(int* __restrict__ partials, int nb) {  // nb <= 256
    __shared__ int sdata[SCAN_BLOCK];
    int v = (threadIdx.x < nb) ? partials[threadIdx.x] : 0;
    sdata[threadIdx.x] = v;
    __syncthreads();
    for (int off = 1; off < SCAN_BLOCK; off <<= 1) {
        int t = (threadIdx.x >= off) ? sdata[threadIdx.x - off] : 0;
        __syncthreads();
        sdata[threadIdx.x] += t;
        __syncthreads();
    }
    if (threadIdx.x < nb) partials[threadIdx.x] = sdata[threadIdx.x] - v;
}

__global__ void k_scan3(int* __restrict__ out, const int* __restrict__ partials, int n) {
    int i = blockIdx.x * blockDim.x + threadIdx.x;
    if (i < n) out[i] += partials[i / (SCAN_BLOCK * SCAN_ITEMS)];
}

// fill adjacency; B[n] starts as exclusive offset, ends as end(n)
__global__ void k_fill(const int* __restrict__ u_idx, const int* __restrict__ i_idx,
                       int* __restrict__ B, int* __restrict__ adj, int E, int num_users) {
    int e = blockIdx.x * blockDim.x + threadIdx.x;
    if (e < E) {
        int u = u_idx[e];
        int ig = num_users + i_idx[e];
        int p = atomicAdd(&B[u], 1);
        adj[p] = ig;
        int q = atomicAdd(&B[ig], 1);
        adj[q] = u;
    }
}

// ---- gather smooths ---------------------------------------------------------
// one 64-lane wave per node, lane = dim; after k_fill, row range of node n is
// [ n==0 ? 0 : B[n-1],  B[n] )

// x1[n] = dis[n] * sum_nbr dis[nbr] * x0[nbr], x0 split across u_emb/i_emb
__global__ void k_smooth1(const int* __restrict__ B, const int* __restrict__ adj,
                          const float* __restrict__ dis,
                          const float* __restrict__ u_emb, const float* __restrict__ i_emb,
                          float* __restrict__ x1, int N, int num_users) {
    int n = blockIdx.x * (blockDim.x >> 6) + (threadIdx.x >> 6);
    int lane = threadIdx.x & 63;
    if (n >= N) return;
    int end = B[n];
    int start = (n == 0) ? 0 : B[n - 1];
    float acc = 0.0f;
    for (int base = start; base < end; base += 64) {
        int cnt = min(64, end - base);
        int nid = 0;
        float wv = 0.0f;
        if (lane < cnt) {
            nid = adj[base + lane];
            wv = dis[nid];
        }
        for (int j = 0; j < cnt; j++) {
            int nj = __shfl(nid, j);
            float wj = __shfl(wv, j);
            const float* src = (nj < num_users) ? (u_emb + (size_t)nj * EMB_D)
                                                : (i_emb + (size_t)(nj - num_users) * EMB_D);
            acc += wj * src[lane];
        }
    }
    x1[(size_t)n * EMB_D + lane] = dis[n] * acc;
}

// out[n] = (2*x0[n] + 2*x1[n] + dis[n]*sum_nbr dis[nbr]*x1[nbr]) / 3
__global__ void k_smooth2(const int* __restrict__ B, const int* __restrict__ adj,
                          const float* __restrict__ dis,
                          const float* __restrict__ u_emb, const float* __restrict__ i_emb,
                          const float* __restrict__ x1, float* __restrict__ out,
                          int N, int num_users) {
    int n = blockIdx.x * (blockDim.x >> 6) + (threadIdx.x >> 6);
    int lane = threadIdx.x & 63;
    if (n >= N) return;
    int end = B[n];
    int start = (n == 0) ? 0 : B[n - 1];
    float acc = 0.0f;
    for (int base = start; base < end; base += 64) {
        int cnt = min(64, end - base);
        int nid = 0;
        float wv = 0.0f;
        if (lane < cnt) {
            nid = adj[base + lane];
            wv = dis[nid];
        }
        for (int j = 0; j < cnt; j++) {
            int nj = __shfl(nid, j);
            float wj = __shfl(wv, j);
            acc += wj * x1[(size_t)nj * EMB_D + lane];
        }
    }
    size_t o = (size_t)n * EMB_D + lane;
    float x0v = (n < num_users) ? u_emb[o] : i_emb[o - (size_t)num_users * EMB_D];
    float x1v = x1[o];
    out[o] = (2.0f * x0v + 2.0f * x1v + dis[n] * acc) * (1.0f / 3.0f);
}

// ---- launch -----------------------------------------------------------------

extern "C" void kernel_launch(void* const* d_in, const int* in_sizes, int n_in,
                              void* d_out, int out_size, void* d_ws, size_t ws_size,
                              hipStream_t stream) {
    const float* u_emb = (const float*)d_in[0];
    const float* i_emb = (const float*)d_in[1];
    const int*   u_idx = (const int*)d_in[2];
    const int*   i_idx = (const int*)d_in[3];
    float* out = (float*)d_out;

    const int num_users = in_sizes[0] / EMB_D;
    const int num_items = in_sizes[1] / EMB_D;
    const int E = in_sizes[2];
    const int N = num_users + num_items;
    const int adjE = 2 * E;  // directed edge count

    // workspace layout (256B-aligned slices)
    auto align_up = [](size_t x) { return (x + 255) & ~(size_t)255; };
    char* p = (char*)d_ws;
    int*   counts   = (int*)p;   p += align_up((size_t)N * 4);
    float* dis      = (float*)p; p += align_up((size_t)N * 4);
    int*   B        = (int*)p;   p += align_up((size_t)N * 4);
    int*   partials = (int*)p;   p += align_up((size_t)SCAN_BLOCK * 4);
    int*   adj      = (int*)p;   p += align_up((size_t)adjE * 4);
    float* x1       = (float*)p;

    hipMemsetAsync(counts, 0, (size_t)N * 4, stream);

    const int blk = 256;
    // 1) degree histogram
    k_hist<<<(E + blk - 1) / blk, blk, 0, stream>>>(u_idx, i_idx, counts, E, num_users);
    // 2) dis = rsqrt(deg)
    k_dis<<<(N + blk - 1) / blk, blk, 0, stream>>>(counts, dis, N);
    // 3) exclusive scan counts -> B
    int nb = (N + SCAN_BLOCK * SCAN_ITEMS - 1) / (SCAN_BLOCK * SCAN_ITEMS);  // 196 for N=200k
    k_scan1<<<nb, SCAN_BLOCK, 0, stream>>>(counts, B, partials, N);
    k_scan2<<<1, SCAN_BLOCK, 0, stream>>>(partials, nb);
    k_scan3<<<(N + blk - 1) / blk, blk, 0, stream>>>(B, partials, N);
    // 4) fill adjacency (B becomes end offsets)
    k_fill<<<(E + blk - 1) / blk, blk, 0, stream>>>(u_idx, i_idx, B, adj, E, num_users);
    // 5) x1 = smooth(x0)
    int nodes_per_blk = blk / 64;
    int ggrid = (N + nodes_per_blk - 1) / nodes_per_blk;
    k_smooth1<<<ggrid, blk, 0, stream>>>(B, adj, dis, u_emb, i_emb, x1, N, num_users);
    // 6) out = (2*x0 + 2*x1 + smooth(x1)) / 3
    k_smooth2<<<ggrid, blk, 0, stream>>>(B, adj, dis, u_emb, i_emb, x1, out, N, num_users);
}

// Round 3
// 524.320 us; speedup vs baseline: 2.4057x; 1.4631x over previous
//
#include <hip/hip_runtime.h>

#define EMB_D 64
#define SCAN_BLOCK 256
#define SCAN_ITEMS 4            // 1024 elements per scan block
#define NGRP 8                  // destination-range groups (≈ XCD count)

// ---- CSR build --------------------------------------------------------------

// degree histogram (int atomics into 800 KB, L2-resident)
__global__ void k_hist(const int* __restrict__ u_idx, const int* __restrict__ i_idx,
                       int* __restrict__ counts, int E, int num_users) {
    int e = blockIdx.x * blockDim.x + threadIdx.x;
    if (e < E) {
        atomicAdd(&counts[u_idx[e]], 1);
        atomicAdd(&counts[num_users + i_idx[e]], 1);
    }
}

// dis[n] = deg>0 ? rsqrt(deg) : 0
__global__ void k_dis(const int* __restrict__ counts, float* __restrict__ dis, int N) {
    int n = blockIdx.x * blockDim.x + threadIdx.x;
    if (n < N) {
        int c = counts[n];
        dis[n] = c > 0 ? rsqrtf((float)c) : 0.0f;
    }
}

// 3-kernel exclusive scan: counts[N] -> B[N]
__global__ void k_scan1(const int* __restrict__ in, int* __restrict__ out,
                        int* __restrict__ partials, int n) {
    __shared__ int sdata[SCAN_BLOCK];
    int idx = blockIdx.x * (SCAN_BLOCK * SCAN_ITEMS) + threadIdx.x * SCAN_ITEMS;
    int v[SCAN_ITEMS];
    int s = 0;
    for (int k = 0; k < SCAN_ITEMS; k++) {
        v[k] = (idx + k < n) ? in[idx + k] : 0;
        s += v[k];
    }
    sdata[threadIdx.x] = s;
    __syncthreads();
    for (int off = 1; off < SCAN_BLOCK; off <<= 1) {
        int t = (threadIdx.x >= off) ? sdata[threadIdx.x - off] : 0;
        __syncthreads();
        sdata[threadIdx.x] += t;
        __syncthreads();
    }
    int incl = sdata[threadIdx.x];
    int excl = incl - s;
    if (threadIdx.x == SCAN_BLOCK - 1) partials[blockIdx.x] = incl;
    int run = excl;
    for (int k = 0; k < SCAN_ITEMS; k++) {
        if (idx + k < n) out[idx + k] = run;
        run += v[k];
    }
}

__global__ void k_scan2(int* __restrict__ partials, int nb) {  // nb <= 256
    __shared__ int sdata[SCAN_BLOCK];
    int v = (threadIdx.x < nb) ? partials[threadIdx.x] : 0;
    sdata[threadIdx.x] = v;
    __syncthreads();
    for (int off = 1; off < SCAN_BLOCK; off <<= 1) {
        int t = (threadIdx.x >= off) ? sdata[threadIdx.x - off] : 0;
        __syncthreads();
        sdata[threadIdx.x] += t;
        __syncthreads();
    }
    if (threadIdx.x < nb) partials[threadIdx.x] = sdata[threadIdx.x] - v;
}

__global__ void k_scan3(int* __restrict__ out, const int* __restrict__ partials, int n) {
    int i = blockIdx.x * blockDim.x + threadIdx.x;
    if (i < n) out[i] += partials[i / (SCAN_BLOCK * SCAN_ITEMS)];
}

// Destination-range-partitioned adjacency fill.
// Group g = blockIdx % NGRP handles only destinations in [g*range, (g+1)*range):
// each group's scattered writes stay inside a ~1.6 MB window (L2-resident,
// lines fully filled before eviction) instead of spraying the whole 10 MB.
// blockIdx % 8 ≈ XCD round-robin, so the window is (heuristically) XCD-local.
__global__ void k_fill_part(const int* __restrict__ u_idx, const int* __restrict__ i_idx,
                            int* __restrict__ B, int* __restrict__ adj,
                            int E, int num_users, int range_size, int blocks_per_grp) {
    int grp = blockIdx.x & (NGRP - 1);
    int lb  = blockIdx.x >> 3;
    int lo = grp * range_size;
    int hi = lo + range_size;
    int stride = blocks_per_grp * blockDim.x;
    for (int e = lb * blockDim.x + threadIdx.x; e < E; e += stride) {
        int u  = u_idx[e];
        int ig = num_users + i_idx[e];
        if (u >= lo && u < hi) {            // edge lands at dst u, neighbor ig
            int p = atomicAdd(&B[u], 1);
            adj[p] = ig;
        }
        if (ig >= lo && ig < hi) {          // edge lands at dst ig, neighbor u
            int q = atomicAdd(&B[ig], 1);
            adj[q] = u;
        }
    }
}

// ---- gather smooths ---------------------------------------------------------
// one 64-lane wave per node, lane = dim; after fill, row range of node n is
// [ n==0 ? 0 : B[n-1],  B[n] )

__device__ __forceinline__ const float* x0row(int nj, const float* __restrict__ ue,
                                              const float* __restrict__ ie, int nu) {
    return (nj < nu) ? (ue + (size_t)nj * EMB_D) : (ie + (size_t)(nj - nu) * EMB_D);
}

// x1[n] = dis[n] * sum_nbr dis[nbr] * x0[nbr]
__global__ void k_smooth1(const int* __restrict__ B, const int* __restrict__ adj,
                          const float* __restrict__ dis,
                          const float* __restrict__ u_emb, const float* __restrict__ i_emb,
                          float* __restrict__ x1, int N, int num_users) {
    int n = blockIdx.x * (blockDim.x >> 6) + (threadIdx.x >> 6);
    int lane = threadIdx.x & 63;
    if (n >= N) return;
    int end = B[n];
    int start = (n == 0) ? 0 : B[n - 1];
    float a0 = 0.f, a1 = 0.f, a2 = 0.f, a3 = 0.f;
    for (int base = start; base < end; base += 64) {
        int cnt = min(64, end - base);
        int nid = 0;
        float wv = 0.0f;
        if (lane < cnt) {
            nid = adj[base + lane];
            wv = dis[nid];
        }
        int j = 0;
        for (; j + 3 < cnt; j += 4) {
            int n0 = __shfl(nid, j),     n1 = __shfl(nid, j + 1);
            int n2 = __shfl(nid, j + 2), n3 = __shfl(nid, j + 3);
            float w0 = __shfl(wv, j),     w1 = __shfl(wv, j + 1);
            float w2 = __shfl(wv, j + 2), w3 = __shfl(wv, j + 3);
            a0 += w0 * x0row(n0, u_emb, i_emb, num_users)[lane];
            a1 += w1 * x0row(n1, u_emb, i_emb, num_users)[lane];
            a2 += w2 * x0row(n2, u_emb, i_emb, num_users)[lane];
            a3 += w3 * x0row(n3, u_emb, i_emb, num_users)[lane];
        }
        for (; j < cnt; j++) {
            int nj = __shfl(nid, j);
            float wj = __shfl(wv, j);
            a0 += wj * x0row(nj, u_emb, i_emb, num_users)[lane];
        }
    }
    x1[(size_t)n * EMB_D + lane] = dis[n] * ((a0 + a1) + (a2 + a3));
}

// out[n] = (2*x0[n] + 2*x1[n] + dis[n]*sum_nbr dis[nbr]*x1[nbr]) / 3
__global__ void k_smooth2(const int* __restrict__ B, const int* __restrict__ adj,
                          const float* __restrict__ dis,
                          const float* __restrict__ u_emb, const float* __restrict__ i_emb,
                          const float* __restrict__ x1, float* __restrict__ out,
                          int N, int num_users) {
    int n = blockIdx.x * (blockDim.x >> 6) + (threadIdx.x >> 6);
    int lane = threadIdx.x & 63;
    if (n >= N) return;
    int end = B[n];
    int start = (n == 0) ? 0 : B[n - 1];
    float a0 = 0.f, a1 = 0.f, a2 = 0.f, a3 = 0.f;
    for (int base = start; base < end; base += 64) {
        int cnt = min(64, end - base);
        int nid = 0;
        float wv = 0.0f;
        if (lane < cnt) {
            nid = adj[base + lane];
            wv = dis[nid];
        }
        int j = 0;
        for (; j + 3 < cnt; j += 4) {
            int n0 = __shfl(nid, j),     n1 = __shfl(nid, j + 1);
            int n2 = __shfl(nid, j + 2), n3 = __shfl(nid, j + 3);
            float w0 = __shfl(wv, j),     w1 = __shfl(wv, j + 1);
            float w2 = __shfl(wv, j + 2), w3 = __shfl(wv, j + 3);
            a0 += w0 * x1[(size_t)n0 * EMB_D + lane];
            a1 += w1 * x1[(size_t)n1 * EMB_D + lane];
            a2 += w2 * x1[(size_t)n2 * EMB_D + lane];
            a3 += w3 * x1[(size_t)n3 * EMB_D + lane];
        }
        for (; j < cnt; j++) {
            int nj = __shfl(nid, j);
            float wj = __shfl(wv, j);
            a0 += wj * x1[(size_t)nj * EMB_D + lane];
        }
    }
    size_t o = (size_t)n * EMB_D + lane;
    float x0v = (n < num_users) ? u_emb[o] : i_emb[o - (size_t)num_users * EMB_D];
    float x1v = x1[o];
    out[o] = (2.0f * x0v + 2.0f * x1v + dis[n] * ((a0 + a1) + (a2 + a3))) * (1.0f / 3.0f);
}

// ---- launch -----------------------------------------------------------------

extern "C" void kernel_launch(void* const* d_in, const int* in_sizes, int n_in,
                              void* d_out, int out_size, void* d_ws, size_t ws_size,
                              hipStream_t stream) {
    const float* u_emb = (const float*)d_in[0];
    const float* i_emb = (const float*)d_in[1];
    const int*   u_idx = (const int*)d_in[2];
    const int*   i_idx = (const int*)d_in[3];
    float* out = (float*)d_out;

    const int num_users = in_sizes[0] / EMB_D;
    const int num_items = in_sizes[1] / EMB_D;
    const int E = in_sizes[2];
    const int N = num_users + num_items;
    const int adjE = 2 * E;

    // workspace layout (256B-aligned slices)
    auto align_up = [](size_t x) { return (x + 255) & ~(size_t)255; };
    char* p = (char*)d_ws;
    int*   counts   = (int*)p;   p += align_up((size_t)N * 4);
    float* dis      = (float*)p; p += align_up((size_t)N * 4);
    int*   B        = (int*)p;   p += align_up((size_t)N * 4);
    int*   partials = (int*)p;   p += align_up((size_t)SCAN_BLOCK * 4);
    int*   adj      = (int*)p;   p += align_up((size_t)adjE * 4);
    float* x1       = (float*)p;

    hipMemsetAsync(counts, 0, (size_t)N * 4, stream);

    const int blk = 256;
    // 1) degree histogram
    k_hist<<<(E + blk - 1) / blk, blk, 0, stream>>>(u_idx, i_idx, counts, E, num_users);
    // 2) dis = rsqrt(deg)
    k_dis<<<(N + blk - 1) / blk, blk, 0, stream>>>(counts, dis, N);
    // 3) exclusive scan counts -> B
    int nb = (N + SCAN_BLOCK * SCAN_ITEMS - 1) / (SCAN_BLOCK * SCAN_ITEMS);
    k_scan1<<<nb, SCAN_BLOCK, 0, stream>>>(counts, B, partials, N);
    k_scan2<<<1, SCAN_BLOCK, 0, stream>>>(partials, nb);
    k_scan3<<<(N + blk - 1) / blk, blk, 0, stream>>>(B, partials, N);
    // 4) fill adjacency, destination-range partitioned (B becomes end offsets)
    {
        int range_size = (N + NGRP - 1) / NGRP;
        int blocks_per_grp = 1024;
        k_fill_part<<<NGRP * blocks_per_grp, blk, 0, stream>>>(
            u_idx, i_idx, B, adj, E, num_users, range_size, blocks_per_grp);
    }
    // 5) x1 = smooth(x0)
    int nodes_per_blk = blk / 64;
    int ggrid = (N + nodes_per_blk - 1) / nodes_per_blk;
    k_smooth1<<<ggrid, blk, 0, stream>>>(B, adj, dis, u_emb, i_emb, x1, N, num_users);
    // 6) out = (2*x0 + 2*x1 + smooth(x1)) / 3
    k_smooth2<<<ggrid, blk, 0, stream>>>(B, adj, dis, u_emb, i_emb, x1, out, N, num_users);
}

// Round 6
// 494.683 us; speedup vs baseline: 2.5498x; 1.0599x over previous
//
#include <hip/hip_runtime.h>

#define EMB_D 64
#define SCAN_BLOCK 256
#define SCAN_ITEMS 4            // 1024 elements per scan block
#define NGRP 8                  // destination-range groups (≈ XCD count)

typedef unsigned short u16;
typedef unsigned int u32;

// fp32 -> bf16 RNE
__device__ __forceinline__ u16 f2bf(float f) {
    u32 u = __float_as_uint(f);
    u32 r = (u + 0x7FFFu + ((u >> 16) & 1u)) >> 16;
    return (u16)r;
}
// bf16 -> fp32 (exact)
__device__ __forceinline__ float bf2f(u16 us) {
    return __uint_as_float((u32)us << 16);
}

// ---- CSR build --------------------------------------------------------------

__global__ void k_hist(const int* __restrict__ u_idx, const int* __restrict__ i_idx,
                       int* __restrict__ counts, int E, int num_users) {
    int e = blockIdx.x * blockDim.x + threadIdx.x;
    if (e < E) {
        atomicAdd(&counts[u_idx[e]], 1);
        atomicAdd(&counts[num_users + i_idx[e]], 1);
    }
}

__global__ void k_dis(const int* __restrict__ counts, float* __restrict__ dis, int N) {
    int n = blockIdx.x * blockDim.x + threadIdx.x;
    if (n < N) {
        int c = counts[n];
        dis[n] = c > 0 ? rsqrtf((float)c) : 0.0f;
    }
}

__global__ void k_scan1(const int* __restrict__ in, int* __restrict__ out,
                        int* __restrict__ partials, int n) {
    __shared__ int sdata[SCAN_BLOCK];
    int idx = blockIdx.x * (SCAN_BLOCK * SCAN_ITEMS) + threadIdx.x * SCAN_ITEMS;
    int v[SCAN_ITEMS];
    int s = 0;
    for (int k = 0; k < SCAN_ITEMS; k++) {
        v[k] = (idx + k < n) ? in[idx + k] : 0;
        s += v[k];
    }
    sdata[threadIdx.x] = s;
    __syncthreads();
    for (int off = 1; off < SCAN_BLOCK; off <<= 1) {
        int t = (threadIdx.x >= off) ? sdata[threadIdx.x - off] : 0;
        __syncthreads();
        sdata[threadIdx.x] += t;
        __syncthreads();
    }
    int incl = sdata[threadIdx.x];
    int excl = incl - s;
    if (threadIdx.x == SCAN_BLOCK - 1) partials[blockIdx.x] = incl;
    int run = excl;
    for (int k = 0; k < SCAN_ITEMS; k++) {
        if (idx + k < n) out[idx + k] = run;
        run += v[k];
    }
}

__global__ void k_scan2(int* __restrict__ partials, int nb) {
    __shared__ int sdata[SCAN_BLOCK];
    int v = (threadIdx.x < nb) ? partials[threadIdx.x] : 0;
    sdata[threadIdx.x] = v;
    __syncthreads();
    for (int off = 1; off < SCAN_BLOCK; off <<= 1) {
        int t = (threadIdx.x >= off) ? sdata[threadIdx.x - off] : 0;
        __syncthreads();
        sdata[threadIdx.x] += t;
        __syncthreads();
    }
    if (threadIdx.x < nb) partials[threadIdx.x] = sdata[threadIdx.x] - v;
}

__global__ void k_scan3(int* __restrict__ out, const int* __restrict__ partials, int n) {
    int i = blockIdx.x * blockDim.x + threadIdx.x;
    if (i < n) out[i] += partials[i / (SCAN_BLOCK * SCAN_ITEMS)];
}

// destination-range-partitioned adjacency fill (writes stay in ~1.6 MB window)
__global__ void k_fill_part(const int* __restrict__ u_idx, const int* __restrict__ i_idx,
                            int* __restrict__ B, int* __restrict__ adj,
                            int E, int num_users, int range_size, int blocks_per_grp) {
    int grp = blockIdx.x & (NGRP - 1);
    int lb  = blockIdx.x >> 3;
    int lo = grp * range_size;
    int hi = lo + range_size;
    int stride = blocks_per_grp * blockDim.x;
    for (int e = lb * blockDim.x + threadIdx.x; e < E; e += stride) {
        int u  = u_idx[e];
        int ig = num_users + i_idx[e];
        if (u >= lo && u < hi) {
            int p = atomicAdd(&B[u], 1);
            adj[p] = ig;
        }
        if (ig >= lo && ig < hi) {
            int q = atomicAdd(&B[ig], 1);
            adj[q] = u;
        }
    }
}

// ---- prescale: xc0[n] = bf16( dis[n] * x0[n] ), x0 = concat(u_emb, i_emb) ---
__global__ void k_prescale(const float* __restrict__ ue, const float* __restrict__ ie,
                           const float* __restrict__ dis, u16* __restrict__ xc,
                           int nuD, int totD) {
    int i4 = (blockIdx.x * blockDim.x + threadIdx.x) * 4;
    if (i4 >= totD) return;
    float d = dis[i4 >> 6];
    const float* src = (i4 < nuD) ? (ue + i4) : (ie + (i4 - nuD));
    float4 v = *(const float4*)src;
    u32 p01 = (u32)f2bf(d * v.x) | ((u32)f2bf(d * v.y) << 16);
    u32 p23 = (u32)f2bf(d * v.z) | ((u32)f2bf(d * v.w) << 16);
    *(uint2*)(xc + i4) = make_uint2(p01, p23);
}

// ---- gather smooths ---------------------------------------------------------
// row range of node n: [ n==0 ? 0 : B[n-1], B[n] ); one 64-lane wave per node

// xc1[n] = bf16( dis[n]^2 * sum_nbr xc0[nbr] )
__global__ void k_smooth1(const int* __restrict__ B, const int* __restrict__ adj,
                          const float* __restrict__ dis, const u16* __restrict__ xc0,
                          u16* __restrict__ xc1, int N) {
    int n = blockIdx.x * (blockDim.x >> 6) + (threadIdx.x >> 6);
    int lane = threadIdx.x & 63;
    if (n >= N) return;
    int end = B[n];
    int start = (n == 0) ? 0 : B[n - 1];
    float a0 = 0.f, a1 = 0.f, a2 = 0.f, a3 = 0.f;
    for (int base = start; base < end; base += 64) {
        int cnt = min(64, end - base);
        int nid = 0;
        if (lane < cnt) nid = adj[base + lane];
        int j = 0;
        for (; j + 3 < cnt; j += 4) {
            int n0 = __shfl(nid, j),     n1 = __shfl(nid, j + 1);
            int n2 = __shfl(nid, j + 2), n3 = __shfl(nid, j + 3);
            a0 += bf2f(xc0[(size_t)n0 * EMB_D + lane]);
            a1 += bf2f(xc0[(size_t)n1 * EMB_D + lane]);
            a2 += bf2f(xc0[(size_t)n2 * EMB_D + lane]);
            a3 += bf2f(xc0[(size_t)n3 * EMB_D + lane]);
        }
        for (; j < cnt; j++) {
            int nj = __shfl(nid, j);
            a0 += bf2f(xc0[(size_t)nj * EMB_D + lane]);
        }
    }
    float d = dis[n];
    xc1[(size_t)n * EMB_D + lane] = f2bf(d * d * ((a0 + a1) + (a2 + a3)));
}

// out[n] = (2*x0[n] + 2*x1[n] + dis[n]*sum_nbr xc1[nbr]) / 3,
// x1[n] = xc1[n] * sqrt(deg[n])
__global__ void k_smooth2(const int* __restrict__ B, const int* __restrict__ adj,
                          const float* __restrict__ dis, const int* __restrict__ counts,
                          const float* __restrict__ u_emb, const float* __restrict__ i_emb,
                          const u16* __restrict__ xc1, float* __restrict__ out,
                          int N, int num_users) {
    int n = blockIdx.x * (blockDim.x >> 6) + (threadIdx.x >> 6);
    int lane = threadIdx.x & 63;
    if (n >= N) return;
    int end = B[n];
    int start = (n == 0) ? 0 : B[n - 1];
    float a0 = 0.f, a1 = 0.f, a2 = 0.f, a3 = 0.f;
    for (int base = start; base < end; base += 64) {
        int cnt = min(64, end - base);
        int nid = 0;
        if (lane < cnt) nid = adj[base + lane];
        int j = 0;
        for (; j + 3 < cnt; j += 4) {
            int n0 = __shfl(nid, j),     n1 = __shfl(nid, j + 1);
            int n2 = __shfl(nid, j + 2), n3 = __shfl(nid, j + 3);
            a0 += bf2f(xc1[(size_t)n0 * EMB_D + lane]);
            a1 += bf2f(xc1[(size_t)n1 * EMB_D + lane]);
            a2 += bf2f(xc1[(size_t)n2 * EMB_D + lane]);
            a3 += bf2f(xc1[(size_t)n3 * EMB_D + lane]);
        }
        for (; j < cnt; j++) {
            int nj = __shfl(nid, j);
            a0 += bf2f(xc1[(size_t)nj * EMB_D + lane]);
        }
    }
    size_t o = (size_t)n * EMB_D + lane;
    float x0v = (n < num_users) ? u_emb[o] : i_emb[o - (size_t)num_users * EMB_D];
    float x1v = bf2f(xc1[o]) * sqrtf((float)counts[n]);   // deg==0 -> 0*0 = 0
    out[o] = (2.0f * x0v + 2.0f * x1v + dis[n] * ((a0 + a1) + (a2 + a3))) * (1.0f / 3.0f);
}

// ---- launch -----------------------------------------------------------------

extern "C" void kernel_launch(void* const* d_in, const int* in_sizes, int n_in,
                              void* d_out, int out_size, void* d_ws, size_t ws_size,
                              hipStream_t stream) {
    const float* u_emb = (const float*)d_in[0];
    const float* i_emb = (const float*)d_in[1];
    const int*   u_idx = (const int*)d_in[2];
    const int*   i_idx = (const int*)d_in[3];
    float* out = (float*)d_out;

    const int num_users = in_sizes[0] / EMB_D;
    const int num_items = in_sizes[1] / EMB_D;
    const int E = in_sizes[2];
    const int N = num_users + num_items;
    const int adjE = 2 * E;
    const int totD = N * EMB_D;
    const int nuD = num_users * EMB_D;

    // workspace layout (256B-aligned slices): ~64 MB total
    auto align_up = [](size_t x) { return (x + 255) & ~(size_t)255; };
    char* p = (char*)d_ws;
    int*   counts   = (int*)p;   p += align_up((size_t)N * 4);
    float* dis      = (float*)p; p += align_up((size_t)N * 4);
    int*   B        = (int*)p;   p += align_up((size_t)N * 4);
    int*   partials = (int*)p;   p += align_up((size_t)SCAN_BLOCK * 4);
    int*   adj      = (int*)p;   p += align_up((size_t)adjE * 4);
    u16*   xc0      = (u16*)p;   p += align_up((size_t)totD * 2);
    u16*   xc1      = (u16*)p;

    hipMemsetAsync(counts, 0, (size_t)N * 4, stream);

    const int blk = 256;
    // 1) degree histogram
    k_hist<<<(E + blk - 1) / blk, blk, 0, stream>>>(u_idx, i_idx, counts, E, num_users);
    // 2) dis = rsqrt(deg)
    k_dis<<<(N + blk - 1) / blk, blk, 0, stream>>>(counts, dis, N);
    // 3) exclusive scan counts -> B
    int nb = (N + SCAN_BLOCK * SCAN_ITEMS - 1) / (SCAN_BLOCK * SCAN_ITEMS);
    k_scan1<<<nb, SCAN_BLOCK, 0, stream>>>(counts, B, partials, N);
    k_scan2<<<1, SCAN_BLOCK, 0, stream>>>(partials, nb);
    k_scan3<<<(N + blk - 1) / blk, blk, 0, stream>>>(B, partials, N);
    // 4) fill adjacency (B becomes end offsets)
    {
        int range_size = (N + NGRP - 1) / NGRP;
        int blocks_per_grp = 1024;
        k_fill_part<<<NGRP * blocks_per_grp, blk, 0, stream>>>(
            u_idx, i_idx, B, adj, E, num_users, range_size, blocks_per_grp);
    }
    // 5) xc0 = bf16(dis * x0)
    k_prescale<<<(totD / 4 + blk - 1) / blk, blk, 0, stream>>>(u_emb, i_emb, dis, xc0, nuD, totD);
    // 6) xc1 = bf16(dis^2 * sum xc0[nbr])
    int nodes_per_blk = blk / 64;
    int ggrid = (N + nodes_per_blk - 1) / nodes_per_blk;
    k_smooth1<<<ggrid, blk, 0, stream>>>(B, adj, dis, xc0, xc1, N);
    // 7) out = (2*x0 + 2*x1 + dis*sum xc1[nbr]) / 3
    k_smooth2<<<ggrid, blk, 0, stream>>>(B, adj, dis, counts, u_emb, i_emb, xc1, out,
                                         N, num_users);
}